// Round 12
// baseline (7091.293 us; speedup 1.0000x reference)
//
#include <hip/hip_runtime.h>
#include <math.h>

#define Bsz 512
#define Tsz 512
#define Fin 32
#define Hd 64
#define CHUNK 32
#define NCH (Tsz / CHUNK)
#define SG 8                  // subgroup: steps per ax-precompute batch

typedef float v2f __attribute__((ext_vector_type(2)));

// v_rcp_f32-based activations (no IEEE div sequence; ~1 ulp)
__device__ __forceinline__ float fsig(float x) {
    return __builtin_amdgcn_rcpf(1.0f + __expf(-x));
}
__device__ __forceinline__ float ftanh(float x) {
    return fmaf(2.0f, __builtin_amdgcn_rcpf(1.0f + __expf(-2.0f * x)), -1.0f);
}

// Pin float4 components into arch VGPRs (blocks AGPR parking; round-3 proven).
#define PIN4(v4) \
    asm volatile("" : "+v"((v4).x), "+v"((v4).y), "+v"((v4).z), "+v"((v4).w))

// ---------------- Layer 0: x[B,T,32] -> h1[B,T,64] ----------------
// R12 = R3 champion + subgroup x-dot hoist. Thread tid's x-projection result
// is consumed only by thread tid, so per 8-step subgroup each thread
// precomputes ax[0..7] into registers (fully unrolled, dependency-free,
// pipe-saturating). The serial loop then carries only the h-dot (16 b128),
// activation, stride-5 glds gate exchange, and c-update: serial-phase LDS
// reads 32->16, VALU ~84->~50 per step, totals per CU unchanged.
// Discriminator: win => serial-stream-bound; null => LDS-throughput-bound.
__global__ __launch_bounds__(256, 2)
void lstm_layer0(const float* __restrict__ x,
                 const float4* __restrict__ Wih4,
                 const float4* __restrict__ Whh4,
                 const float* __restrict__ bih,
                 const float* __restrict__ bhh,
                 float* __restrict__ h1out)
{
    __shared__ __align__(16) float xbuf[2][CHUNK * Fin]; // 2 x 4KB
    __shared__ __align__(16) float hcopy[4][Hd];         // per-wave private h
    __shared__ float glds[2][Hd * 5];                    // gates, stride 5

    const int tid  = threadIdx.x;
    const int lane = tid & 63;
    const int wv   = tid >> 6;
    const int wvu  = __builtin_amdgcn_readfirstlane(wv);
    const int b    = blockIdx.x;

    float4 wih[8];
#pragma unroll
    for (int q = 0; q < 8; ++q) wih[q] = Wih4[tid * 8 + q];
    float4 whh[16];
#pragma unroll
    for (int q = 0; q < 16; ++q) whh[q] = Whh4[tid * 16 + q];
    const float bias = bih[tid] + bhh[tid];

    float c = 0.0f;
    hcopy[wv][lane] = 0.0f;

    const float4* xsrc = (const float4*)(x + (size_t)b * Tsz * Fin);
    ((float4*)xbuf[0])[tid] = xsrc[tid];
    float* hout = h1out + (size_t)b * Tsz * Hd + lane;
    __syncthreads();

    for (int ci = 0; ci < NCH; ++ci) {
        const int cur = ci & 1;
        if (ci + 1 < NCH)
            ((float4*)xbuf[cur ^ 1])[tid] = xsrc[(ci + 1) * (CHUNK * Fin / 4) + tid];
#pragma unroll
        for (int q = 0; q < 8; ++q)  PIN4(wih[q]);
#pragma unroll
        for (int q = 0; q < 16; ++q) PIN4(whh[q]);
#pragma unroll 1
        for (int sg = 0; sg < CHUNK / SG; ++sg) {
            // ---- phase P: x-projections for the next 8 steps (no deps) ----
            float ax[SG];
#pragma unroll
            for (int j = 0; j < SG; ++j) {
                const float4* xr =
                    (const float4*)&xbuf[cur][(sg * SG + j) * Fin];
                v2f a0 = {bias, 0.0f}, a1 = {0.0f, 0.0f};
#pragma unroll
                for (int q = 0; q < 8; ++q) {
                    float4 xv = xr[q];
                    v2f b0 = {xv.x, xv.y}, b1 = {xv.z, xv.w};
                    v2f w0 = {wih[q].x, wih[q].y}, w1 = {wih[q].z, wih[q].w};
                    a0 = __builtin_elementwise_fma(b0, w0, a0);
                    a1 = __builtin_elementwise_fma(b1, w1, a1);
                }
                ax[j] = (a0.x + a0.y) + (a1.x + a1.y);
            }
            // ---- serial phase: 8 thin recurrence steps ----
#pragma unroll
            for (int j = 0; j < SG; ++j) {
                const int t = ci * CHUNK + sg * SG + j;
                const int p = t & 1;
                const float4* hrow = (const float4*)&hcopy[wv][0];
                v2f a0 = {ax[j], 0.0f}, a1 = {0.0f, 0.0f};
#pragma unroll
                for (int q = 0; q < 16; ++q) {
                    float4 hv = hrow[q];
                    v2f b0 = {hv.x, hv.y}, b1 = {hv.z, hv.w};
                    v2f w0 = {whh[q].x, whh[q].y}, w1 = {whh[q].z, whh[q].w};
                    a0 = __builtin_elementwise_fma(b0, w0, a0);
                    a1 = __builtin_elementwise_fma(b1, w1, a1);
                }
                float a = (a0.x + a0.y) + (a1.x + a1.y);
                if (wvu == 2) glds[p][lane * 5 + wv] = ftanh(a);
                else          glds[p][lane * 5 + wv] = fsig(a);
                __syncthreads();
                float gi = glds[p][lane * 5 + 0];
                float gf = glds[p][lane * 5 + 1];
                float gg = glds[p][lane * 5 + 2];
                float go = glds[p][lane * 5 + 3];
                c = fmaf(gf, c, gi * gg);
                float h = go * ftanh(c);
                hcopy[wv][lane] = h;               // own-wave, in-order
                if (wvu == 0) hout[(size_t)t * Hd] = h;
            }
        }
    }
}

// ------- Layer 1 + FC: h1[B,T,64] -> out[B] -------
__global__ __launch_bounds__(256, 2)
void lstm_layer1_fc(const float* __restrict__ h1,
                    const float4* __restrict__ Wih4,
                    const float4* __restrict__ Whh4,
                    const float* __restrict__ bih,
                    const float* __restrict__ bhh,
                    const float* __restrict__ fcW,
                    const float* __restrict__ fcb,
                    float* __restrict__ out)
{
    __shared__ __align__(16) float xbuf[2][CHUNK * Hd]; // 2 x 8KB
    __shared__ __align__(16) float hcopy[4][Hd];
    __shared__ float glds[2][Hd * 5];

    const int tid  = threadIdx.x;
    const int lane = tid & 63;
    const int wv   = tid >> 6;
    const int wvu  = __builtin_amdgcn_readfirstlane(wv);
    const int b    = blockIdx.x;

    float4 wih[16];
#pragma unroll
    for (int q = 0; q < 16; ++q) wih[q] = Wih4[tid * 16 + q];
    float4 whh[16];
#pragma unroll
    for (int q = 0; q < 16; ++q) whh[q] = Whh4[tid * 16 + q];
    const float bias = bih[tid] + bhh[tid];

    float c  = 0.0f;
    float hl = 0.0f;
    hcopy[wv][lane] = 0.0f;

    const float4* xsrc = (const float4*)(h1 + (size_t)b * Tsz * Hd);
    ((float4*)xbuf[0])[tid]       = xsrc[tid];
    ((float4*)xbuf[0])[tid + 256] = xsrc[tid + 256];
    __syncthreads();

    for (int ci = 0; ci < NCH; ++ci) {
        const int cur = ci & 1;
        if (ci + 1 < NCH) {
            ((float4*)xbuf[cur ^ 1])[tid]       = xsrc[(ci + 1) * (CHUNK * Hd / 4) + tid];
            ((float4*)xbuf[cur ^ 1])[tid + 256] = xsrc[(ci + 1) * (CHUNK * Hd / 4) + tid + 256];
        }
#pragma unroll
        for (int q = 0; q < 16; ++q) PIN4(wih[q]);
#pragma unroll
        for (int q = 0; q < 16; ++q) PIN4(whh[q]);
#pragma unroll 1
        for (int sg = 0; sg < CHUNK / SG; ++sg) {
            // ---- phase P: x-projections for the next 8 steps ----
            float ax[SG];
#pragma unroll
            for (int j = 0; j < SG; ++j) {
                const float4* xr =
                    (const float4*)&xbuf[cur][(sg * SG + j) * Hd];
                v2f a0 = {bias, 0.0f}, a1 = {0.0f, 0.0f};
#pragma unroll
                for (int q = 0; q < 16; ++q) {
                    float4 xv = xr[q];
                    v2f b0 = {xv.x, xv.y}, b1 = {xv.z, xv.w};
                    v2f w0 = {wih[q].x, wih[q].y}, w1 = {wih[q].z, wih[q].w};
                    a0 = __builtin_elementwise_fma(b0, w0, a0);
                    a1 = __builtin_elementwise_fma(b1, w1, a1);
                }
                ax[j] = (a0.x + a0.y) + (a1.x + a1.y);
            }
            // ---- serial phase: 8 thin recurrence steps ----
#pragma unroll
            for (int j = 0; j < SG; ++j) {
                const int t = ci * CHUNK + sg * SG + j;
                const int p = t & 1;
                const float4* hrow = (const float4*)&hcopy[wv][0];
                v2f a0 = {ax[j], 0.0f}, a1 = {0.0f, 0.0f};
#pragma unroll
                for (int q = 0; q < 16; ++q) {
                    float4 hv = hrow[q];
                    v2f b0 = {hv.x, hv.y}, b1 = {hv.z, hv.w};
                    v2f w0 = {whh[q].x, whh[q].y}, w1 = {whh[q].z, whh[q].w};
                    a0 = __builtin_elementwise_fma(b0, w0, a0);
                    a1 = __builtin_elementwise_fma(b1, w1, a1);
                }
                float a = (a0.x + a0.y) + (a1.x + a1.y);
                if (wvu == 2) glds[p][lane * 5 + wv] = ftanh(a);
                else          glds[p][lane * 5 + wv] = fsig(a);
                __syncthreads();
                float gi = glds[p][lane * 5 + 0];
                float gf = glds[p][lane * 5 + 1];
                float gg = glds[p][lane * 5 + 2];
                float go = glds[p][lane * 5 + 3];
                c  = fmaf(gf, c, gi * gg);
                hl = go * ftanh(c);
                hcopy[wv][lane] = hl;
            }
        }
    }
    // fused FC on last h2 (wave 0 only; hl is replicated across waves)
    if (wvu == 0) {
        float psum = hl * fcW[lane];
#pragma unroll
        for (int off = 32; off > 0; off >>= 1)
            psum += __shfl_down(psum, off);
        if (lane == 0) out[b] = psum + fcb[0];
    }
}

extern "C" void kernel_launch(void* const* d_in, const int* in_sizes, int n_in,
                              void* d_out, int out_size, void* d_ws, size_t ws_size,
                              hipStream_t stream)
{
    const float* x    = (const float*)d_in[0];
    const float* Wih0 = (const float*)d_in[1];
    const float* Whh0 = (const float*)d_in[2];
    const float* bih0 = (const float*)d_in[3];
    const float* bhh0 = (const float*)d_in[4];
    const float* Wih1 = (const float*)d_in[5];
    const float* Whh1 = (const float*)d_in[6];
    const float* bih1 = (const float*)d_in[7];
    const float* bhh1 = (const float*)d_in[8];
    const float* fcW  = (const float*)d_in[9];
    const float* fcb  = (const float*)d_in[10];
    float* out = (float*)d_out;
    float* h1  = (float*)d_ws; // B*T*H fp32 = 64 MB scratch

    lstm_layer0<<<dim3(Bsz), dim3(256), 0, stream>>>(
        x, (const float4*)Wih0, (const float4*)Whh0, bih0, bhh0, h1);
    lstm_layer1_fc<<<dim3(Bsz), dim3(256), 0, stream>>>(
        h1, (const float4*)Wih1, (const float4*)Whh1, bih1, bhh1, fcW, fcb, out);
}

// Round 13
// 1068.060 us; speedup vs baseline: 6.6394x; 6.6394x over previous
//
#include <hip/hip_runtime.h>
#include <math.h>

#define Bsz 512
#define Tsz 512
#define Fin 32
#define Hd 64
#define BB 16              // batch rows per block
#define NBLK (Bsz / BB)    // 32 blocks

typedef float f32x4 __attribute__((ext_vector_type(4)));
typedef _Float16 f16x8 __attribute__((ext_vector_type(8)));
typedef _Float16 f16x4 __attribute__((ext_vector_type(4)));

__device__ __forceinline__ float fsig(float x) {
    return __builtin_amdgcn_rcpf(1.0f + __expf(-x));
}
__device__ __forceinline__ float ftanh(float x) {
    return fmaf(2.0f, __builtin_amdgcn_rcpf(1.0f + __expf(-2.0f * x)), -1.0f);
}
__device__ __forceinline__ f32x4 MFMA(f16x8 a, f16x8 b, f32x4 c) {
    return __builtin_amdgcn_mfma_f32_16x16x32_f16(a, b, c, 0, 0, 0);
}

// ============================================================================
// R13: MFMA recurrence. 16 batch rows per block (grid=32 — the recurrence is
// latency-bound; idle CUs don't matter, only step_time does). Per step the
// 16x256 gate pre-activations are computed as D = X_t*Wih^T + H_t*Whh^T + b
// on the matrix pipe: A-fragments = inputs (split-f16 hi+lo for fp32-level
// accuracy: AhBh + AhBl + AlBh), B-fragments = weights^T, split-f16,
// PRELOADED IN REGISTERS once per kernel. 8 waves; wave w owns N-tiles
// {w, w+8} (gate q=w>>2 sigmoid, and gate 2+(w>>2): tanh for w<4).
// Fragment layouts: A lane l -> A[l&15][8*(l>>4)+j]; B lane l ->
// B[8*(l>>4)+j][l&15]; C/D col=lane&15, row=(lane>>4)*4+reg (m89-verified).
// A-slabs in LDS are XOR-swizzled (byte ^= (row&m)<<4) for conflict-free
// ds_read_b128. Gate exchange via +65-padded LDS buffer. Two barriers/step.
// x staged per 8-step group, double-buffered, global loads prefetched one
// group ahead (held in regs, ~4000-cycle distance).
// ============================================================================
template <int K, bool LAST>
__global__ __launch_bounds__(512, 1)
void lstm_mfma(const float* __restrict__ X,     // [B,T,K] layer input
               const float* __restrict__ Wih,   // [256,K]
               const float* __restrict__ Whh,   // [256,64]
               const float* __restrict__ bih,
               const float* __restrict__ bhh,
               float* __restrict__ hout,        // !LAST: h1 [B,T,64]
               const float* __restrict__ fcW,   // LAST only
               const float* __restrict__ fcb,
               float* __restrict__ out)
{
    constexpr int KS    = K / 32;         // x-GEMM k-slices (1 or 2)
    constexpr int RB    = K * 2;          // bytes per x-slab row
    constexpr int XSLAB = 16 * RB;        // one timestep's A-slab
    constexpr int XBUF  = 8 * XSLAB;      // one 8-step group
    constexpr int SWM   = (K == 64) ? 7 : 3;
    constexpr int F4R   = K / 4;          // float4 per input row
    constexpr int NPF   = (128 * F4R) / 512;

    __shared__ __align__(16) _Float16 xAh[2 * 8 * 16 * K];
    __shared__ __align__(16) _Float16 xAl[2 * 8 * 16 * K];
    __shared__ __align__(16) _Float16 hAh[2 * 16 * 64];
    __shared__ __align__(16) _Float16 hAl[2 * 16 * 64];
    __shared__ float gx[2][4][16][65];    // [parity][gate][batch][dim+pad]

    char* const xAhB = (char*)xAh;
    char* const xAlB = (char*)xAl;
    char* const hAhB = (char*)hAh;
    char* const hAlB = (char*)hAl;

    const int tid = threadIdx.x;
    const int l   = tid & 63;
    const int wv  = tid >> 6;                         // 0..7
    const int wvu = __builtin_amdgcn_readfirstlane(wv);
    const int lr  = l & 15;
    const int lg  = l >> 4;
    const int b0  = blockIdx.x * BB;

    // ---- B-fragments (weights^T, split f16), ntiles {wv, wv+8} ----
    f16x8 wihH[2][KS], wihL[2][KS], whhH[2][2], whhL[2][2];
    float bb[2];
#pragma unroll
    for (int nt = 0; nt < 2; ++nt) {
        const int r = (wv + nt * 8) * 16 + lr;        // gate row (N col)
#pragma unroll
        for (int ks = 0; ks < KS; ++ks) {
            f16x8 hi, lo;
#pragma unroll
            for (int j = 0; j < 8; ++j) {
                float w = Wih[(size_t)r * K + ks * 32 + lg * 8 + j];
                _Float16 wh = (_Float16)w;
                hi[j] = wh; lo[j] = (_Float16)(w - (float)wh);
            }
            wihH[nt][ks] = hi; wihL[nt][ks] = lo;
        }
#pragma unroll
        for (int ks = 0; ks < 2; ++ks) {
            f16x8 hi, lo;
#pragma unroll
            for (int j = 0; j < 8; ++j) {
                float w = Whh[(size_t)r * 64 + ks * 32 + lg * 8 + j];
                _Float16 wh = (_Float16)w;
                hi[j] = wh; lo[j] = (_Float16)(w - (float)wh);
            }
            whhH[nt][ks] = hi; whhL[nt][ks] = lo;
        }
        bb[nt] = bih[r] + bhh[r];
    }

    // c/h ownership: thread -> (bown, dd0) and (bown, dd1)
    const int bown = tid >> 5;            // 0..15
    const int dd0  = tid & 31;
    const int dd1  = 32 + dd0;
    float c0 = 0.f, c1 = 0.f, h0 = 0.f, h1v = 0.f;

    const float4* Xg4 = (const float4*)X;
    float4 pf[NPF];

    // prefetch loads for group gg (held in registers)
    auto pload = [&](int gg) {
#pragma unroll
        for (int i = 0; i < NPF; ++i) {
            const int idx  = tid + i * 512;
            const int pair = idx / F4R;
            const int j    = idx % F4R;
            const int bl   = pair >> 3;
            const int tl   = pair & 7;
            pf[i] = Xg4[((size_t)(b0 + bl) * Tsz + gg * 8 + tl) * F4R + j];
        }
    };
    // split-convert pf regs into A-slab buffer gbuf
    auto stage = [&](int gbuf) {
#pragma unroll
        for (int i = 0; i < NPF; ++i) {
            const int idx  = tid + i * 512;
            const int pair = idx / F4R;
            const int j    = idx % F4R;
            const int bl   = pair >> 3;
            const int tl   = pair & 7;
            float4 v = pf[i];
            f16x4 hi, lo;
            _Float16 t;
            t = (_Float16)v.x; hi[0] = t; lo[0] = (_Float16)(v.x - (float)t);
            t = (_Float16)v.y; hi[1] = t; lo[1] = (_Float16)(v.y - (float)t);
            t = (_Float16)v.z; hi[2] = t; lo[2] = (_Float16)(v.z - (float)t);
            t = (_Float16)v.w; hi[3] = t; lo[3] = (_Float16)(v.w - (float)t);
            const int off = gbuf * XBUF + tl * XSLAB + bl * RB +
                            ((j * 8) ^ ((bl & SWM) << 4));
            *(f16x4*)(xAhB + off) = hi;
            *(f16x4*)(xAlB + off) = lo;
        }
    };

    // ---- prologue: stage group 0, prefetch group 1, zero hA[0] ----
    pload(0);
    stage(0);
    pload(1);
    {
        const int o0 = bown * 128 + ((dd0 * 2) ^ ((bown & 7) << 4));
        const int o1 = bown * 128 + ((dd1 * 2) ^ ((bown & 7) << 4));
        *(_Float16*)(hAhB + o0) = (_Float16)0.f;
        *(_Float16*)(hAlB + o0) = (_Float16)0.f;
        *(_Float16*)(hAhB + o1) = (_Float16)0.f;
        *(_Float16*)(hAlB + o1) = (_Float16)0.f;
    }
    __syncthreads();

    const int q0  = wvu >> 2;                  // 0:i or 1:f (sigmoid)
    const int dwr = (wvu & 3) * 16 + lr;       // dim col for gate writes

#pragma unroll 1
    for (int t = 0; t < Tsz; ++t) {
        const int p = t & 1, s = t & 7, g = t >> 3, buf = g & 1;
        if (s == 0 && g >= 1 && g + 1 < 64) pload(g + 1);

        // A-fragments: x (this step's slab) and h (parity p)
        f16x8 xah[KS], xal[KS];
#pragma unroll
        for (int ks = 0; ks < KS; ++ks) {
            const int off = buf * XBUF + s * XSLAB + lr * RB +
                            ((ks * 64 + lg * 16) ^ ((lr & SWM) << 4));
            xah[ks] = *(const f16x8*)(xAhB + off);
            xal[ks] = *(const f16x8*)(xAlB + off);
        }
        f16x8 hah[2], hal[2];
#pragma unroll
        for (int ks = 0; ks < 2; ++ks) {
            const int off = p * 2048 + lr * 128 +
                            ((ks * 64 + lg * 16) ^ ((lr & 7) << 4));
            hah[ks] = *(const f16x8*)(hAhB + off);
            hal[ks] = *(const f16x8*)(hAlB + off);
        }

        // GEMM: a = bias + x*Wih^T + h*Whh^T  (split-f16: hh + hl + lh)
        f32x4 a0 = {bb[0], bb[0], bb[0], bb[0]};
        f32x4 a1 = {bb[1], bb[1], bb[1], bb[1]};
        f32x4 e0 = {0.f, 0.f, 0.f, 0.f};
        f32x4 e1 = {0.f, 0.f, 0.f, 0.f};
#pragma unroll
        for (int ks = 0; ks < KS; ++ks) {
            a0 = MFMA(xah[ks], wihH[0][ks], a0);
            a1 = MFMA(xah[ks], wihH[1][ks], a1);
            e0 = MFMA(xal[ks], wihH[0][ks], e0);
            e1 = MFMA(xal[ks], wihH[1][ks], e1);
            a0 = MFMA(xah[ks], wihL[0][ks], a0);
            a1 = MFMA(xah[ks], wihL[1][ks], a1);
        }
#pragma unroll
        for (int ks = 0; ks < 2; ++ks) {
            a0 = MFMA(hah[ks], whhH[0][ks], a0);
            a1 = MFMA(hah[ks], whhH[1][ks], a1);
            e0 = MFMA(hal[ks], whhH[0][ks], e0);
            e1 = MFMA(hal[ks], whhH[1][ks], e1);
            a0 = MFMA(hah[ks], whhL[0][ks], a0);
            a1 = MFMA(hah[ks], whhL[1][ks], a1);
        }
        a0 += e0;
        a1 += e1;

        // activations + gate exchange write (D row = lg*4+reg = batch)
#pragma unroll
        for (int rg = 0; rg < 4; ++rg)
            gx[p][q0][lg * 4 + rg][dwr] = fsig(a0[rg]);
        if (wvu < 4) {
#pragma unroll
            for (int rg = 0; rg < 4; ++rg)
                gx[p][2][lg * 4 + rg][dwr] = ftanh(a1[rg]);
        } else {
#pragma unroll
            for (int rg = 0; rg < 4; ++rg)
                gx[p][3][lg * 4 + rg][dwr] = fsig(a1[rg]);
        }
        __syncthreads();   // B1: gates visible

        // c/h update for the 2 owned (b,d) pairs
        float gi = gx[p][0][bown][dd0], gf = gx[p][1][bown][dd0];
        float gg = gx[p][2][bown][dd0], go = gx[p][3][bown][dd0];
        c0  = fmaf(gf, c0, gi * gg);
        h0  = go * ftanh(c0);
        gi = gx[p][0][bown][dd1]; gf = gx[p][1][bown][dd1];
        gg = gx[p][2][bown][dd1]; go = gx[p][3][bown][dd1];
        c1  = fmaf(gf, c1, gi * gg);
        h1v = go * ftanh(c1);

        // write next step's h A-fragments (split f16, swizzled)
        {
            const int o0 = (p ^ 1) * 2048 + bown * 128 +
                           ((dd0 * 2) ^ ((bown & 7) << 4));
            _Float16 hh = (_Float16)h0;
            *(_Float16*)(hAhB + o0) = hh;
            *(_Float16*)(hAlB + o0) = (_Float16)(h0 - (float)hh);
            const int o1 = (p ^ 1) * 2048 + bown * 128 +
                           ((dd1 * 2) ^ ((bown & 7) << 4));
            hh = (_Float16)h1v;
            *(_Float16*)(hAhB + o1) = hh;
            *(_Float16*)(hAlB + o1) = (_Float16)(h1v - (float)hh);
        }
        if constexpr (!LAST) {
            float* hp = hout + ((size_t)(b0 + bown) * Tsz + t) * Hd;
            hp[dd0] = h0;
            hp[dd1] = h1v;
        }
        if (s == 7 && g + 1 < 64) stage((g + 1) & 1);
        __syncthreads();   // B2: hA / xA handoff
    }

    if constexpr (LAST) {
        // FC over dims: reduce within each 32-lane (same-b) group
        float psum = h0 * fcW[dd0] + h1v * fcW[dd1];
#pragma unroll
        for (int off = 16; off > 0; off >>= 1)
            psum += __shfl_down(psum, off, 32);
        if ((tid & 31) == 0) out[b0 + bown] = psum + fcb[0];
    }
}

extern "C" void kernel_launch(void* const* d_in, const int* in_sizes, int n_in,
                              void* d_out, int out_size, void* d_ws, size_t ws_size,
                              hipStream_t stream)
{
    const float* x    = (const float*)d_in[0];
    const float* Wih0 = (const float*)d_in[1];
    const float* Whh0 = (const float*)d_in[2];
    const float* bih0 = (const float*)d_in[3];
    const float* bhh0 = (const float*)d_in[4];
    const float* Wih1 = (const float*)d_in[5];
    const float* Whh1 = (const float*)d_in[6];
    const float* bih1 = (const float*)d_in[7];
    const float* bhh1 = (const float*)d_in[8];
    const float* fcW  = (const float*)d_in[9];
    const float* fcb  = (const float*)d_in[10];
    float* out = (float*)d_out;
    float* h1  = (float*)d_ws;   // B*T*H fp32 = 67.1 MB (known to fit)

    lstm_mfma<Fin, false><<<dim3(NBLK), dim3(512), 0, stream>>>(
        x, Wih0, Whh0, bih0, bhh0, h1, nullptr, nullptr, nullptr);
    lstm_mfma<Hd, true><<<dim3(NBLK), dim3(512), 0, stream>>>(
        h1, Wih1, Whh1, bih1, bhh1, nullptr, fcW, fcb, out);
}